// Round 4
// baseline (114687.073 us; speedup 1.0000x reference)
//
#include <hip/hip_runtime.h>
#include <cmath>

// ---------------------------------------------------------------------------
// LPCNet-style vocoder on MI355X — round 4.
// R3 post-mortem: asm "+v" pin failed (VGPR_Count=128; loads rematerialized
// into the loop -> ~4us/step L2 re-stream) and un-skewed h reads cost 2.6e8
// LDS bank-conflict cycles. Fix:
//   * W_h half -> 192 AGPRs/thread via v_accvgpr_write (opaque asm defs are
//     NOT rematerializable -> guaranteed register residency).
//   * out_w half -> 64 pinned VGPRs/thread via opaque v_mov.
//   * h layout skewed (HSTRIDE=68) -> conflict-free float4 broadcasts.
// Per-step global traffic is now ~zero (gic row + output writes only).
// ---------------------------------------------------------------------------

#define NB 8
#define NF 64
#define ND 20
#define NH 256
#define NG 768      // 3*NH
#define FS 160
#define NT (NF * FS)   // 10240
#define HSTRIDE 68     // 64 + 4 pad floats per h-group (bank-quad skew)

#define AGENT __HIP_MEMORY_SCOPE_AGENT

#define AG_W(dst, src) asm volatile("v_accvgpr_write_b32 %0, %1" : "=a"(dst) : "v"(src))
#define AG_R(dst, src) asm volatile("v_accvgpr_read_b32 %0, %1" : "=v"(dst) : "a"(src))
#define VPIN(dst, src) asm volatile("v_mov_b32 %0, %1" : "=v"(dst) : "v"(src))

__device__ __forceinline__ void st_ag(float* p, float v) {
    __hip_atomic_store(p, v, __ATOMIC_RELAXED, AGENT);
}
__device__ __forceinline__ float ld_ag(float* p) {
    return __hip_atomic_load(p, __ATOMIC_RELAXED, AGENT);
}
__device__ __forceinline__ void st_ag_i(int* p, int v) {
    __hip_atomic_store(p, v, __ATOMIC_RELAXED, AGENT);
}
__device__ __forceinline__ int ld_ag_i(int* p) {
    return __hip_atomic_load(p, __ATOMIC_RELAXED, AGENT);
}

// ---------------------------------------------------------------------------
// Kernel A: FrameRateNet + gi_cond precompute (unchanged, passing).
// ---------------------------------------------------------------------------
__global__ __launch_bounds__(128) void frn_kernel(
    const float* __restrict__ feat,
    const float* __restrict__ w1,
    const float* __restrict__ b1,
    const float* __restrict__ w2,
    const float* __restrict__ b2,
    const float* __restrict__ fw1,
    const float* __restrict__ fb1,
    const float* __restrict__ fw2,
    const float* __restrict__ fb2,
    const float* __restrict__ wi,
    const float* __restrict__ bi,
    float* __restrict__ gic)
{
    const int bf = blockIdx.x;
    const int b = bf >> 6;
    const int f = bf & 63;
    const int o = threadIdx.x;

    __shared__ float sfeat[5][ND];
    __shared__ float sc1[3][128];
    __shared__ float sc2[128];
    __shared__ float sc3[128];
    __shared__ float scond[128];

    for (int i = o; i < 5 * ND; i += 128) {
        int ff = f - 2 + i / ND;
        int c = i % ND;
        sfeat[i / ND][c] = (ff >= 0 && ff < NF) ? feat[((size_t)b * NF + ff) * ND + c] : 0.f;
    }
    __syncthreads();

    for (int df = 0; df < 3; ++df) {
        int fp = f - 1 + df;
        if (fp >= 0 && fp < NF) {
            float acc = b1[o];
            for (int k = 0; k < 3; ++k)
                for (int c = 0; c < ND; ++c)
                    acc += sfeat[df + k][c] * w1[(k * ND + c) * 128 + o];
            sc1[df][o] = tanhf(acc);
        } else {
            sc1[df][o] = 0.f;
        }
    }
    __syncthreads();

    {
        float acc = b2[o];
        for (int k = 0; k < 3; ++k)
            for (int c = 0; c < 128; ++c)
                acc += sc1[k][c] * w2[(k * 128 + c) * 128 + o];
        sc2[o] = tanhf(acc);
    }
    __syncthreads();
    {
        float acc = fb1[o];
        for (int c = 0; c < 128; ++c) acc += sc2[c] * fw1[c * 128 + o];
        sc3[o] = tanhf(acc);
    }
    __syncthreads();
    {
        float acc = fb2[o];
        for (int c = 0; c < 128; ++c) acc += sc3[c] * fw2[c * 128 + o];
        scond[o] = tanhf(acc);
    }
    __syncthreads();

    for (int r = 0; r < 6; ++r) {
        int j = o + 128 * r;
        float acc = bi[j];
        const float* wr = wi + (size_t)j * 129 + 1;
        for (int c = 0; c < 128; ++c) acc += scond[c] * wr[c];
        gic[(size_t)bf * NG + j] = acc;
    }
}

// ---------------------------------------------------------------------------
// Kernel B: AR loop, 16 blocks (pair bid^8 -> same XCD under mod-8 mapping),
// 512 threads. All weights register-resident (AGPR + pinned VGPR).
// ---------------------------------------------------------------------------
__global__ __launch_bounds__(512, 2) void ar_kernel(
    const float* __restrict__ gic,    // (8*64, 768)
    const float* __restrict__ wh,     // (768,256) fp32
    const float* __restrict__ ow,     // (256,256) [c][o] native
    const float* __restrict__ wi,     // (768,129)
    const float* __restrict__ bh,     // (768,)
    const float* __restrict__ ob,     // (256,)
    float* __restrict__ wav_out,      // (8, 10240)
    float* __restrict__ logits_out,   // (8, 10240, 256)
    int* flagH, int* flagM,           // [16] each
    float* hx,                        // [16][2][128]
    float* xmv, int* xmi)             // [16][2]
{
    const int bid = blockIdx.x;
    const int b = bid & 7;            // batch
    const int k = bid >> 3;           // half (partner = bid ^ 8)
    const int t = threadIdx.x;
    const int qq = t >> 2;            // 0..127 : local hidden row
    const int ss = t & 3;             // K-quarter (64 cols)
    const int ol = t & 127;           // logits: local o
    const int cp = t >> 7;            // logits: c-quarter

    __shared__ __align__(16) float hsp[4 * HSTRIDE];  // h, skew-padded groups
    __shared__ float pgh[4][388];                     // [ss][qq*3+r]
    __shared__ float pl[4][132];                      // [cp][ol]
    __shared__ float candv[2];
    __shared__ int   candi[2];
    __shared__ float sprev;

    // ---- W_h half -> 192 AGPRs (opaque defs: cannot be rematerialized) ----
    float A0[64], A1[64], A2[64];
    {
        const float4* wb = (const float4*)wh;           // row = 64 float4
        size_t base = (size_t)(128 * k + qq) * 64 + (size_t)ss * 16;
        #pragma unroll
        for (int i = 0; i < 16; ++i) {
            float4 x0 = wb[base + i];
            float4 x1 = wb[base + 256 * 64 + i];
            float4 x2 = wb[base + 512 * 64 + i];
            AG_W(A0[4*i+0], x0.x); AG_W(A0[4*i+1], x0.y);
            AG_W(A0[4*i+2], x0.z); AG_W(A0[4*i+3], x0.w);
            AG_W(A1[4*i+0], x1.x); AG_W(A1[4*i+1], x1.y);
            AG_W(A1[4*i+2], x1.z); AG_W(A1[4*i+3], x1.w);
            AG_W(A2[4*i+0], x2.x); AG_W(A2[4*i+1], x2.y);
            AG_W(A2[4*i+2], x2.z); AG_W(A2[4*i+3], x2.w);
        }
    }
    // ---- out_w half -> 64 pinned VGPRs: OW[j] = ow[cp*64+j][128k+ol] ----
    float OW[64];
    {
        #pragma unroll
        for (int j = 0; j < 64; ++j) {
            float x = ow[(size_t)(cp * 64 + j) * NH + 128 * k + ol];
            VPIN(OW[j], x);
        }
    }

    // ---- per-thread gate/output scalars (threads 0..127 = own hidden half) ----
    float bh_r = 0, bh_z = 0, bh_n = 0, wi_r = 0, wi_z = 0, wi_n = 0, ob_o = 0;
    if (t < 128) {
        int gr = 128 * k + t;
        bh_r = bh[gr]; bh_z = bh[gr + 256]; bh_n = bh[gr + 512];
        wi_r = wi[(size_t)gr * 129];
        wi_z = wi[(size_t)(gr + 256) * 129];
        wi_n = wi[(size_t)(gr + 512) * 129];
        ob_o = ob[gr];
    }

    if (t < NH) hsp[(t >> 6) * HSTRIDE + (t & 63)] = 0.f;
    if (t == 0) sprev = 0.f;
    float yacc = 0.f;
    __syncthreads();

    const float* gicb = gic + (size_t)b * NF * NG;
    float* lob = logits_out + (size_t)b * NT * NH;
    float* wob = wav_out + (size_t)b * NT;

    for (int st = 0; st <= NT; ++st) {
        // ---- Phase A: P1_st (gh from h_{st-1}, AGPR) + P3_{st-1} (logits, VGPR) ----
        if (st < NT) {
            const float4* h4 = (const float4*)hsp;
            float a0 = 0.f, a1 = 0.f, a2 = 0.f;
            #pragma unroll
            for (int i = 0; i < 16; ++i) {
                float4 hv = h4[ss * (HSTRIDE / 4) + i];
                float w;
                AG_R(w, A0[4*i+0]); a0 += w * hv.x;
                AG_R(w, A0[4*i+1]); a0 += w * hv.y;
                AG_R(w, A0[4*i+2]); a0 += w * hv.z;
                AG_R(w, A0[4*i+3]); a0 += w * hv.w;
                AG_R(w, A1[4*i+0]); a1 += w * hv.x;
                AG_R(w, A1[4*i+1]); a1 += w * hv.y;
                AG_R(w, A1[4*i+2]); a1 += w * hv.z;
                AG_R(w, A1[4*i+3]); a1 += w * hv.w;
                AG_R(w, A2[4*i+0]); a2 += w * hv.x;
                AG_R(w, A2[4*i+1]); a2 += w * hv.y;
                AG_R(w, A2[4*i+2]); a2 += w * hv.z;
                AG_R(w, A2[4*i+3]); a2 += w * hv.w;
            }
            pgh[ss][qq * 3 + 0] = a0;
            pgh[ss][qq * 3 + 1] = a1;
            pgh[ss][qq * 3 + 2] = a2;
        }
        if (st > 0) {
            const float4* h4 = (const float4*)hsp;
            float a = 0.f;
            #pragma unroll
            for (int j4 = 0; j4 < 16; ++j4) {
                float4 hv = h4[cp * (HSTRIDE / 4) + j4];   // broadcast within wave
                a += OW[4*j4+0] * hv.x + OW[4*j4+1] * hv.y
                   + OW[4*j4+2] * hv.z + OW[4*j4+3] * hv.w;
            }
            pl[cp][ol] = a;
        }
        __syncthreads();

        // ---- Phase B: finalize local logits + store + local argmax ----
        if (st > 0 && t < 128) {
            float lg = ob_o + pl[0][t] + pl[1][t] + pl[2][t] + pl[3][t];
            lob[(size_t)(st - 1) * NH + 128 * k + t] = lg;
            float bv = lg; int bi_ = 128 * k + t;
            #pragma unroll
            for (int d = 32; d > 0; d >>= 1) {
                float ov = __shfl_down(bv, d);
                int   oi = __shfl_down(bi_, d);
                if (ov > bv || (ov == bv && oi < bi_)) { bv = ov; bi_ = oi; }
            }
            if ((t & 63) == 0) { candv[t >> 6] = bv; candi[t >> 6] = bi_; }
        }
        __syncthreads();

        // ---- Phase C: cross-CU max exchange + mu-law sample + de-emphasis ----
        if (st > 0 && t == 0) {
            float mv = candv[0]; int mi = candi[0];
            if (candv[1] > mv || (candv[1] == mv && candi[1] < mi)) { mv = candv[1]; mi = candi[1]; }
            int slot = (st - 1) & 1;
            st_ag(&xmv[bid * 2 + slot], mv);
            st_ag_i(&xmi[bid * 2 + slot], mi);
            __hip_atomic_store(&flagM[bid], st, __ATOMIC_RELEASE, AGENT);
            while (__hip_atomic_load(&flagM[bid ^ 8], __ATOMIC_ACQUIRE, AGENT) < st)
                __builtin_amdgcn_s_sleep(1);
            float rv = ld_ag(&xmv[(bid ^ 8) * 2 + slot]);
            int   ri = ld_ag_i(&xmi[(bid ^ 8) * 2 + slot]);
            if (rv > mv || (rv == mv && ri < mi)) { mv = rv; mi = ri; }
            float v = ((float)mi + 0.5f) * (1.f / 128.f) - 1.f;
            float av = fabsf(v);
            float mag = (exp2f(8.f * av) - 1.f) * (1.f / 255.f);
            float smp = (v >= 0.f) ? mag : -mag;
            sprev = smp;
            yacc = smp + 0.97f * yacc;
            if (k == 0) wob[st - 1] = yacc;
        }
        __syncthreads();

        // ---- Phase D: gates (own half) + h-half exchange ----
        if (st < NT) {
            int slot = st & 1;
            if (t < 128) {
                int gr = 128 * k + t;
                const float* gf = gicb + (size_t)(st / FS) * NG;
                float prev = sprev;
                float s_r = pgh[0][t * 3 + 0] + pgh[1][t * 3 + 0] + pgh[2][t * 3 + 0] + pgh[3][t * 3 + 0];
                float s_z = pgh[0][t * 3 + 1] + pgh[1][t * 3 + 1] + pgh[2][t * 3 + 1] + pgh[3][t * 3 + 1];
                float s_n = pgh[0][t * 3 + 2] + pgh[1][t * 3 + 2] + pgh[2][t * 3 + 2] + pgh[3][t * 3 + 2];
                float sr = gf[gr]       + wi_r * prev + bh_r + s_r;
                float sz = gf[gr + 256] + wi_z * prev + bh_z + s_z;
                float ni = gf[gr + 512] + wi_n * prev;
                float nh = bh_n + s_n;
                float r = 1.f / (1.f + expf(-sr));
                float z = 1.f / (1.f + expf(-sz));
                float n = tanhf(ni + r * nh);
                float hold = hsp[(gr >> 6) * HSTRIDE + (gr & 63)];
                float hn = (1.f - z) * n + z * hold;
                hsp[(gr >> 6) * HSTRIDE + (gr & 63)] = hn;
                st_ag(&hx[(bid * 2 + slot) * 128 + t], hn);
            }
            __syncthreads();
            if (t == 0) {
                __threadfence();
                __hip_atomic_store(&flagH[bid], st + 1, __ATOMIC_RELEASE, AGENT);
                while (__hip_atomic_load(&flagH[bid ^ 8], __ATOMIC_ACQUIRE, AGENT) < st + 1)
                    __builtin_amdgcn_s_sleep(1);
            }
            __syncthreads();
            if (t < 128) {
                int pr = 128 * (1 - k) + t;
                hsp[(pr >> 6) * HSTRIDE + (pr & 63)] =
                    ld_ag(&hx[((bid ^ 8) * 2 + slot) * 128 + t]);
            }
            __syncthreads();
        }
    }
}

// ---------------------------------------------------------------------------
extern "C" void kernel_launch(void* const* d_in, const int* in_sizes, int n_in,
                              void* d_out, int out_size, void* d_ws, size_t ws_size,
                              hipStream_t stream) {
    (void)in_sizes; (void)n_in; (void)out_size; (void)ws_size;

    const float* feat = (const float*)d_in[0];
    const float* c1w  = (const float*)d_in[1];
    const float* c1b  = (const float*)d_in[2];
    const float* c2w  = (const float*)d_in[3];
    const float* c2b  = (const float*)d_in[4];
    const float* f1w  = (const float*)d_in[5];
    const float* f1b  = (const float*)d_in[6];
    const float* f2w  = (const float*)d_in[7];
    const float* f2b  = (const float*)d_in[8];
    const float* gwi  = (const float*)d_in[9];
    const float* gwh  = (const float*)d_in[10];
    const float* gbi  = (const float*)d_in[11];
    const float* gbh  = (const float*)d_in[12];
    const float* outw = (const float*)d_in[13];
    const float* outb = (const float*)d_in[14];

    // workspace layout
    char* ws = (char*)d_ws;
    float* gic  = (float*)ws;                        // 8*64*768 fp32 = 1,572,864 B
    int*  flagH = (int*)(ws + 1572864);              // 64 B
    int*  flagM = (int*)(ws + 1572864 + 64);         // 64 B
    float* hx   = (float*)(ws + 1572864 + 128);      // 16*2*128 fp32 = 16,384 B
    float* xmv  = (float*)(ws + 1572864 + 128 + 16384);      // 128 B
    int*  xmi   = (int*)(ws + 1572864 + 128 + 16384 + 128);  // 128 B

    float* wav    = (float*)d_out;
    float* logits = (float*)d_out + NB * NT;

    // flags must be zeroed every call (ws is re-poisoned to 0xAA)
    hipMemsetAsync(ws + 1572864, 0, 128, stream);

    frn_kernel<<<dim3(NB * NF), dim3(128), 0, stream>>>(
        feat, c1w, c1b, c2w, c2b, f1w, f1b, f2w, f2b, gwi, gbi, gic);
    ar_kernel<<<dim3(16), dim3(512), 0, stream>>>(
        gic, gwh, outw, gwi, gbh, outb, wav, logits,
        flagH, flagM, hx, xmv, xmi);
}

// Round 5
// 34106.638 us; speedup vs baseline: 3.3626x; 3.3626x over previous
//
#include <hip/hip_runtime.h>
#include <cmath>

// ---------------------------------------------------------------------------
// LPCNet-style vocoder on MI355X — round 5: 8-CU-per-batch, single exchange.
// R4 post-mortem: 320 unified regs/thread > 256 budget (512-thr block = 2
// waves/SIMD) -> AGPRs spilled to scratch -> weights re-streamed every step.
// R5: 64 blocks (8 per batch, bid%8==batch -> same-XCD heuristic), 512 thr.
//   * W_h share = 48 fp32/thread in AGPR (3 gate rows x 16 cols).
//   * FULL out_w per CU = 128 fp32/thread pinned VGPR -> logits + argmax +
//     sample computed redundantly & bitwise-identically on all 8 CUs ->
//     NO argmax exchange.
//   * ONE exchange/step: h posted as packed {tag=st+1, f32 h} 8-byte relaxed
//     agent atomics (parity double-buffer). Word-atomicity replaces
//     release/acquire -> no L2 writeback fences, no flag->data round trip.
//   * gh partial reduction via shfl_xor butterfly (no LDS round-trip);
//     h in LDS with 20-float group skew -> conflict-free b128.
// Budget: 48 AGPR + 128 pinned VGPR + ~60 working = ~236 <= 256. Fits.
// ---------------------------------------------------------------------------

#define NB 8
#define NF 64
#define ND 20
#define NH 256
#define NG 768      // 3*NH
#define FS 160
#define NT (NF * FS)   // 10240

#define AGENT __HIP_MEMORY_SCOPE_AGENT
#define HLAY(c) ((((c) >> 4) * 20) + ((c) & 15))   // 16-float groups, 20-float stride

#define AG_W(dst, src) asm volatile("v_accvgpr_write_b32 %0, %1" : "=a"(dst) : "v"(src))
#define AG_R(dst, src) asm volatile("v_accvgpr_read_b32 %0, %1" : "=v"(dst) : "a"(src))
#define VPIN(dst, src) asm volatile("v_mov_b32 %0, %1" : "=v"(dst) : "v"(src))

// ---------------------------------------------------------------------------
// Kernel A: FrameRateNet + gi_cond precompute (unchanged, passing).
// ---------------------------------------------------------------------------
__global__ __launch_bounds__(128) void frn_kernel(
    const float* __restrict__ feat,
    const float* __restrict__ w1,
    const float* __restrict__ b1,
    const float* __restrict__ w2,
    const float* __restrict__ b2,
    const float* __restrict__ fw1,
    const float* __restrict__ fb1,
    const float* __restrict__ fw2,
    const float* __restrict__ fb2,
    const float* __restrict__ wi,
    const float* __restrict__ bi,
    float* __restrict__ gic)
{
    const int bf = blockIdx.x;
    const int b = bf >> 6;
    const int f = bf & 63;
    const int o = threadIdx.x;

    __shared__ float sfeat[5][ND];
    __shared__ float sc1[3][128];
    __shared__ float sc2[128];
    __shared__ float sc3[128];
    __shared__ float scond[128];

    for (int i = o; i < 5 * ND; i += 128) {
        int ff = f - 2 + i / ND;
        int c = i % ND;
        sfeat[i / ND][c] = (ff >= 0 && ff < NF) ? feat[((size_t)b * NF + ff) * ND + c] : 0.f;
    }
    __syncthreads();

    for (int df = 0; df < 3; ++df) {
        int fp = f - 1 + df;
        if (fp >= 0 && fp < NF) {
            float acc = b1[o];
            for (int k = 0; k < 3; ++k)
                for (int c = 0; c < ND; ++c)
                    acc += sfeat[df + k][c] * w1[(k * ND + c) * 128 + o];
            sc1[df][o] = tanhf(acc);
        } else {
            sc1[df][o] = 0.f;
        }
    }
    __syncthreads();

    {
        float acc = b2[o];
        for (int k = 0; k < 3; ++k)
            for (int c = 0; c < 128; ++c)
                acc += sc1[k][c] * w2[(k * 128 + c) * 128 + o];
        sc2[o] = tanhf(acc);
    }
    __syncthreads();
    {
        float acc = fb1[o];
        for (int c = 0; c < 128; ++c) acc += sc2[c] * fw1[c * 128 + o];
        sc3[o] = tanhf(acc);
    }
    __syncthreads();
    {
        float acc = fb2[o];
        for (int c = 0; c < 128; ++c) acc += sc3[c] * fw2[c * 128 + o];
        scond[o] = tanhf(acc);
    }
    __syncthreads();

    for (int r = 0; r < 6; ++r) {
        int j = o + 128 * r;
        float acc = bi[j];
        const float* wr = wi + (size_t)j * 129 + 1;
        for (int c = 0; c < 128; ++c) acc += scond[c] * wr[c];
        gic[(size_t)bf * NG + j] = acc;
    }
}

// ---------------------------------------------------------------------------
// Kernel B: AR loop. 64 blocks (b = bid&7, j = bid>>3), 512 threads.
// ---------------------------------------------------------------------------
__global__ __launch_bounds__(512, 2) void ar_kernel(
    const float* __restrict__ gic,    // (8*64, 768)
    const float* __restrict__ wh,     // (768,256) fp32
    const float* __restrict__ ow,     // (256,256) [c][o] native
    const float* __restrict__ wi,     // (768,129) — need column 0
    const float* __restrict__ bh,     // (768,)
    const float* __restrict__ ob,     // (256,)
    float* __restrict__ wav_out,      // (8, 10240)
    float* __restrict__ logits_out,   // (8, 10240, 256)
    unsigned long long* __restrict__ hxp)  // [8][2][256] packed {tag,h}
{
    const int bid = blockIdx.x;
    const int b = bid & 7;            // batch (bid%8 -> same-XCD heuristic)
    const int j = bid >> 3;           // CU index within batch, 0..7
    const int t = threadIdx.x;
    const int qq = t >> 4;            // 0..31: local hidden unit (P1 rows)
    const int ss = t & 15;            // K-chunk of 16 cols (low 4 lane bits!)
    const int og = t >> 3;            // 0..63: o-group of 4 (P3)
    const int c8 = t & 7;             // c-chunk of 32 (P3)

    __shared__ __align__(16) float hsp[16 * 20];   // h, skewed groups
    __shared__ __align__(16) float pl[8][256];     // logits partials [c8][o]
    __shared__ float ghfin[32][3];                 // reduced gh rows
    __shared__ float candv[4];
    __shared__ int   candi[4];

    // ---- W_h share -> 48 AGPRs: rows {g, g+256, g+512}, g=32j+qq, cols ss*16.. ----
    float A0[16], A1[16], A2[16];
    {
        const float4* wb = (const float4*)wh;      // row = 64 float4
        size_t r0 = (size_t)(32 * j + qq) * 64 + ss * 4;
        #pragma unroll
        for (int i = 0; i < 4; ++i) {
            float4 x0 = wb[r0 + i];
            AG_W(A0[4*i+0], x0.x); AG_W(A0[4*i+1], x0.y);
            AG_W(A0[4*i+2], x0.z); AG_W(A0[4*i+3], x0.w);
        }
        #pragma unroll
        for (int i = 0; i < 4; ++i) {
            float4 x1 = wb[r0 + 256 * 64 + i];
            AG_W(A1[4*i+0], x1.x); AG_W(A1[4*i+1], x1.y);
            AG_W(A1[4*i+2], x1.z); AG_W(A1[4*i+3], x1.w);
        }
        #pragma unroll
        for (int i = 0; i < 4; ++i) {
            float4 x2 = wb[r0 + 512 * 64 + i];
            AG_W(A2[4*i+0], x2.x); AG_W(A2[4*i+1], x2.y);
            AG_W(A2[4*i+2], x2.z); AG_W(A2[4*i+3], x2.w);
        }
    }
    // ---- FULL out_w -> 128 pinned VGPRs: OW4[i] = ow[c8*32+i][og*4..+3] ----
    float4 OW4[32];
    {
        const float4* op = (const float4*)ow;      // row c = 64 float4
        #pragma unroll
        for (int i = 0; i < 32; ++i) {
            float4 x = op[(size_t)(c8 * 32 + i) * 64 + og];
            VPIN(OW4[i].x, x.x); VPIN(OW4[i].y, x.y);
            VPIN(OW4[i].z, x.z); VPIN(OW4[i].w, x.w);
        }
    }

    // ---- per-thread scalars ----
    float bh_r = 0, bh_z = 0, bh_n = 0, wi_r = 0, wi_z = 0, wi_n = 0;
    if (t < 32) {
        int gr = 32 * j + t;
        bh_r = bh[gr]; bh_z = bh[gr + 256]; bh_n = bh[gr + 512];
        wi_r = wi[(size_t)gr * 129];
        wi_z = wi[(size_t)(gr + 256) * 129];
        wi_n = wi[(size_t)(gr + 512) * 129];
    }
    float ob_o = (t < NH) ? ob[t] : 0.f;

    if (t < NH) hsp[HLAY(t)] = 0.f;
    float prev = 0.f, yacc = 0.f;
    __syncthreads();

    const float* gicb = gic + (size_t)b * NF * NG;
    float* lob = logits_out + (size_t)b * NT * NH;
    float* wob = wav_out + (size_t)b * NT;
    unsigned long long* hxb = hxp + (size_t)b * 2 * 256;

    for (int st = 0; st <= NT; ++st) {
        // ---- Phase A: gh_st partials (AGPR) + logits_{st-1} partials (VGPR) ----
        if (st < NT) {
            const float4* h4 = (const float4*)hsp;
            float a0 = 0.f, a1 = 0.f, a2 = 0.f;
            #pragma unroll
            for (int i = 0; i < 4; ++i) {
                float4 hv = h4[ss * 5 + i];
                float w;
                AG_R(w, A0[4*i+0]); a0 += w * hv.x;
                AG_R(w, A0[4*i+1]); a0 += w * hv.y;
                AG_R(w, A0[4*i+2]); a0 += w * hv.z;
                AG_R(w, A0[4*i+3]); a0 += w * hv.w;
                AG_R(w, A1[4*i+0]); a1 += w * hv.x;
                AG_R(w, A1[4*i+1]); a1 += w * hv.y;
                AG_R(w, A1[4*i+2]); a1 += w * hv.z;
                AG_R(w, A1[4*i+3]); a1 += w * hv.w;
                AG_R(w, A2[4*i+0]); a2 += w * hv.x;
                AG_R(w, A2[4*i+1]); a2 += w * hv.y;
                AG_R(w, A2[4*i+2]); a2 += w * hv.z;
                AG_R(w, A2[4*i+3]); a2 += w * hv.w;
            }
            // butterfly over ss (low 4 lane bits) -> all lanes hold row sums
            #pragma unroll
            for (int d = 1; d <= 8; d <<= 1) {
                a0 += __shfl_xor(a0, d);
                a1 += __shfl_xor(a1, d);
                a2 += __shfl_xor(a2, d);
            }
            if (ss == 0) {
                ghfin[qq][0] = a0; ghfin[qq][1] = a1; ghfin[qq][2] = a2;
            }
        }
        if (st > 0) {
            const float4* h4 = (const float4*)hsp;
            float4 acc = {0.f, 0.f, 0.f, 0.f};
            #pragma unroll
            for (int i = 0; i < 8; ++i) {
                float4 hv = h4[(c8 * 2 + (i >> 2)) * 5 + (i & 3)];  // wave-uniform
                acc.x += hv.x * OW4[4*i+0].x; acc.y += hv.x * OW4[4*i+0].y;
                acc.z += hv.x * OW4[4*i+0].z; acc.w += hv.x * OW4[4*i+0].w;
                acc.x += hv.y * OW4[4*i+1].x; acc.y += hv.y * OW4[4*i+1].y;
                acc.z += hv.y * OW4[4*i+1].z; acc.w += hv.y * OW4[4*i+1].w;
                acc.x += hv.z * OW4[4*i+2].x; acc.y += hv.z * OW4[4*i+2].y;
                acc.z += hv.z * OW4[4*i+2].z; acc.w += hv.z * OW4[4*i+2].w;
                acc.x += hv.w * OW4[4*i+3].x; acc.y += hv.w * OW4[4*i+3].y;
                acc.z += hv.w * OW4[4*i+3].z; acc.w += hv.w * OW4[4*i+3].w;
            }
            *(float4*)&pl[c8][og * 4] = acc;
        }
        __syncthreads();   // b1

        // ---- Phase B: finalize logits, store own slice, wave argmax ----
        if (st > 0 && t < NH) {
            float lg = ob_o;
            #pragma unroll
            for (int c = 0; c < 8; ++c) lg += pl[c][t];
            if ((t >> 5) == j) lob[(size_t)(st - 1) * NH + t] = lg;
            float bv = lg; int bi_ = t;
            #pragma unroll
            for (int d = 32; d > 0; d >>= 1) {
                float ov = __shfl_down(bv, d);
                int   oi = __shfl_down(bi_, d);
                if (ov > bv || (ov == bv && oi < bi_)) { bv = ov; bi_ = oi; }
            }
            if ((t & 63) == 0) { candv[t >> 6] = bv; candi[t >> 6] = bi_; }
        }
        __syncthreads();   // b2

        // ---- Phase C: sample (ALL threads, identical on all 8 CUs) ----
        if (st > 0) {
            float mv = candv[0]; int mi = candi[0];
            #pragma unroll
            for (int w = 1; w < 4; ++w) {
                float ov = candv[w]; int oi = candi[w];
                if (ov > mv || (ov == mv && oi < mi)) { mv = ov; mi = oi; }
            }
            float v = ((float)mi + 0.5f) * (1.f / 128.f) - 1.f;
            float av = fabsf(v);
            float mag = (exp2f(8.f * av) - 1.f) * (1.f / 255.f);
            float smp = (v >= 0.f) ? mag : -mag;
            prev = smp;
            yacc = smp + 0.97f * yacc;
            if (j == 0 && t == 0) wob[st - 1] = yacc;
        }

        // ---- Phase D: gates (own 32 units) + packed-atomic h broadcast ----
        if (st < NT) {
            int par = st & 1;
            unsigned tag = (unsigned)(st + 1);
            if (t < 32) {
                int gu = 32 * j + t;
                const float* gf = gicb + (size_t)(st / FS) * NG;
                float sr = gf[gu]       + wi_r * prev + bh_r + ghfin[t][0];
                float sz = gf[gu + 256] + wi_z * prev + bh_z + ghfin[t][1];
                float ni = gf[gu + 512] + wi_n * prev;
                float nh = bh_n + ghfin[t][2];
                float r = 1.f / (1.f + expf(-sr));
                float z = 1.f / (1.f + expf(-sz));
                float n = tanhf(ni + r * nh);
                int hl = HLAY(gu);
                float hn = (1.f - z) * n + z * hsp[hl];
                hsp[hl] = hn;
                unsigned long long pk =
                    ((unsigned long long)tag << 32) | (unsigned long long)__float_as_uint(hn);
                __hip_atomic_store(&hxb[par * 256 + gu], pk, __ATOMIC_RELAXED, AGENT);
            } else if (t >= 64 && t < 288) {
                int gu = (32 * j + (t - 32)) & 255;   // the 224 partner units
                unsigned long long* sl = &hxb[par * 256 + gu];
                unsigned long long pk;
                for (;;) {
                    pk = __hip_atomic_load(sl, __ATOMIC_RELAXED, AGENT);
                    if ((unsigned)(pk >> 32) == tag) break;
                    __builtin_amdgcn_s_sleep(1);
                }
                hsp[HLAY(gu)] = __uint_as_float((unsigned)pk);
            }
        }
        __syncthreads();   // b3
    }
}

// ---------------------------------------------------------------------------
extern "C" void kernel_launch(void* const* d_in, const int* in_sizes, int n_in,
                              void* d_out, int out_size, void* d_ws, size_t ws_size,
                              hipStream_t stream) {
    (void)in_sizes; (void)n_in; (void)out_size; (void)ws_size;

    const float* feat = (const float*)d_in[0];
    const float* c1w  = (const float*)d_in[1];
    const float* c1b  = (const float*)d_in[2];
    const float* c2w  = (const float*)d_in[3];
    const float* c2b  = (const float*)d_in[4];
    const float* f1w  = (const float*)d_in[5];
    const float* f1b  = (const float*)d_in[6];
    const float* f2w  = (const float*)d_in[7];
    const float* f2b  = (const float*)d_in[8];
    const float* gwi  = (const float*)d_in[9];
    const float* gwh  = (const float*)d_in[10];
    const float* gbi  = (const float*)d_in[11];
    const float* gbh  = (const float*)d_in[12];
    const float* outw = (const float*)d_in[13];
    const float* outb = (const float*)d_in[14];

    // workspace layout
    char* ws = (char*)d_ws;
    float* gic = (float*)ws;                                  // 1,572,864 B
    unsigned long long* hxp = (unsigned long long*)(ws + 1572864);  // 8*2*256*8 = 32,768 B
    // tag protocol: 0xAAAAAAAA poison never equals any tag (st+1 <= 10240),
    // so no memset of hxp is required.

    float* wav    = (float*)d_out;                 // (8,10240,1)
    float* logits = (float*)d_out + NB * NT;       // (8,10240,256)

    frn_kernel<<<dim3(NB * NF), dim3(128), 0, stream>>>(
        feat, c1w, c1b, c2w, c2b, f1w, f1b, f2w, f2b, gwi, gbi, gic);
    ar_kernel<<<dim3(64), dim3(512), 0, stream>>>(
        gic, gwh, outw, gwi, gbh, outb, wav, logits, hxp);
}